// Round 1
// baseline (1031.505 us; speedup 1.0000x reference)
//
#include <hip/hip_runtime.h>

#define Hh 480
#define Ww 480
#define Cc 32
#define Bb 32
#define Ll 120
#define CHUNKS 15   // 480*480/15 = 15360 elems = 3840 float4 per chunk; /256 thr = 15 iters

// Kernel 1: per-(batch,chunk) partial sums of the channel-1 agent mask.
// part layout: int[32][CHUNKS][3] = {cnt, sum_y, sum_x}
__global__ __launch_bounds__(256) void agent_pos_partial(const float* __restrict__ in,
                                                         int* __restrict__ part) {
    const int b     = blockIdx.x / CHUNKS;
    const int chunk = blockIdx.x % CHUNKS;
    const float4* ch = (const float4*)(in + ((size_t)b * Cc + 1) * (size_t)(Hh * Ww));
    const int base = chunk * (Hh * Ww / CHUNKS / 4);  // float4 index base

    int cnt = 0, sy = 0, sx = 0;
#pragma unroll
    for (int it = 0; it < 15; ++it) {
        const int fidx = base + it * 256 + threadIdx.x;
        const float4 v = ch[fidx];
        const int lin = fidx * 4;
        if (v.x == 1.0f) { cnt++; sy += (lin    ) / Ww; sx += (lin    ) % Ww; }
        if (v.y == 1.0f) { cnt++; sy += (lin + 1) / Ww; sx += (lin + 1) % Ww; }
        if (v.z == 1.0f) { cnt++; sy += (lin + 2) / Ww; sx += (lin + 2) % Ww; }
        if (v.w == 1.0f) { cnt++; sy += (lin + 3) / Ww; sx += (lin + 3) % Ww; }
    }
    // wave64 shuffle reduction
#pragma unroll
    for (int off = 32; off > 0; off >>= 1) {
        cnt += __shfl_down(cnt, off);
        sy  += __shfl_down(sy,  off);
        sx  += __shfl_down(sx,  off);
    }
    __shared__ int lds[4][3];
    const int wave = threadIdx.x >> 6;
    const int lane = threadIdx.x & 63;
    if (lane == 0) { lds[wave][0] = cnt; lds[wave][1] = sy; lds[wave][2] = sx; }
    __syncthreads();
    if (threadIdx.x == 0) {
        int c = 0, y = 0, x = 0;
#pragma unroll
        for (int w = 0; w < 4; ++w) { c += lds[w][0]; y += lds[w][1]; x += lds[w][2]; }
        int* o = part + ((size_t)b * CHUNKS + chunk) * 3;
        o[0] = c; o[1] = y; o[2] = x;
    }
}

// Kernel 2: one block per (b, y_out); 1 thread per x_out; loop over channels.
__global__ __launch_bounds__(128) void crop_resize(const float* __restrict__ in,
                                                   const int* __restrict__ part,
                                                   float* __restrict__ out) {
    const int b  = blockIdx.x / Ll;
    const int yo = blockIdx.x % Ll;

    // reduce the 15 partials (uniform addresses -> scalar/broadcast loads)
    int cnt = 0, sy = 0, sx = 0;
    const int* p = part + (size_t)b * CHUNKS * 3;
#pragma unroll
    for (int i = 0; i < CHUNKS; ++i) { cnt += p[i*3]; sy += p[i*3+1]; sx += p[i*3+2]; }

    const float denom = fmaxf((float)cnt, 1.0f);
    const int py = (cnt > 0) ? (int)rintf((float)sy / denom) : (Hh / 2);  // rintf = round-half-even, matches jnp.round
    const int px = (cnt > 0) ? (int)rintf((float)sx / denom) : (Ww / 2);

    const int y_start = max(py - Ll / 2, 0);
    const int y_end   = min(py + Ll / 2, Hh);
    const int x_start = max(px - Ll / 2, 0);
    const int x_end   = min(px + Ll / 2, Ww);
    const int ry = y_end - y_start;
    const int rx = x_end - x_start;

    // vertical sample for this output row (same reference arithmetic, fp32)
    const float iy  = (float)yo + 0.5f;
    const float syf = fmaxf(iy * ((float)ry / (float)Ll) - 0.5f, 0.0f);
    const int   y0  = (int)floorf(syf);
    const int   y1  = min(y0 + 1, ry - 1);
    const float wy  = syf - (float)y0;
    const int   ya0 = y_start + y0;
    const int   ya1 = y_start + y1;

    const int x = threadIdx.x;
    if (x >= Ll) return;

    const float ix  = (float)x + 0.5f;
    const float sxf = fmaxf(ix * ((float)rx / (float)Ll) - 0.5f, 0.0f);
    const int   x0  = (int)floorf(sxf);
    const int   x1  = min(x0 + 1, rx - 1);
    const float wx  = sxf - (float)x0;
    const int   xa0 = x_start + x0;
    const int   xa1 = x_start + x1;

    const float* img = in + (size_t)b * Cc * Hh * Ww;
    float* ob = out + (size_t)b * Cc * Ll * Ll + (size_t)yo * Ll + x;

    const int r0 = ya0 * Ww;
    const int r1 = ya1 * Ww;
#pragma unroll 4
    for (int c = 0; c < Cc; ++c) {
        const float* pc = img + (size_t)c * Hh * Ww;
        const float v00 = pc[r0 + xa0];
        const float v01 = pc[r0 + xa1];
        const float v10 = pc[r1 + xa0];
        const float v11 = pc[r1 + xa1];
        const float top = v00 * (1.0f - wx) + v01 * wx;
        const float bot = v10 * (1.0f - wx) + v11 * wx;
        ob[(size_t)c * Ll * Ll] = top * (1.0f - wy) + bot * wy;
    }
}

extern "C" void kernel_launch(void* const* d_in, const int* in_sizes, int n_in,
                              void* d_out, int out_size, void* d_ws, size_t ws_size,
                              hipStream_t stream) {
    const float* in  = (const float*)d_in[0];
    float*       out = (float*)d_out;
    int*         part = (int*)d_ws;   // 32*15*3 ints = 5760 B

    agent_pos_partial<<<Bb * CHUNKS, 256, 0, stream>>>(in, part);
    crop_resize<<<Bb * Ll, 128, 0, stream>>>(in, part, out);
}